// Round 13
// baseline (336.817 us; speedup 1.0000x reference)
//
#include <hip/hip_runtime.h>
#include <hip/hip_bf16.h>
#include <stdint.h>

// ---------------------------------------------------------------------------
// CharToWord v13: bidirectional char-GRU + attention pooling.
// v12 post-mortem: bwd+attn fusion regressed (196 vs 150 split) - reverted.
// Root cause model (validated by counters v6-v11): barrier-coupled latency -
// VALU issue is only ~1/3 of each block-step; all waves wait at the same
// per-step __syncthreads so nothing fills the stalls.
// v13: NO-BARRIER gru. Each wave owns 16 words' FULL recurrence:
//  - Whh' frag table (96 KiB, one dir) staged once in LDS, shared read-only.
//  - per-wave private 4 KiB h-pack in LDS: written at v8-verified hw_off(nt)
//    slots, re-read as B-frags next step. Same-wave DS ops are in-order and
//    data-dependent -> no barrier in the loop at all.
//  - per-wave sorted Lmax trip count; 8 independent waves/block, 1 block/CU.
//  - h rows stored direct from registers (predicated uint2 per nt).
// attn: v8-proven kernel, unchanged. prep/sort unchanged.
// ---------------------------------------------------------------------------

typedef unsigned short u16;
typedef float f32x4 __attribute__((ext_vector_type(4)));
typedef __bf16 bf16x8 __attribute__((ext_vector_type(8)));

#if __has_builtin(__builtin_amdgcn_exp2f)
#define EXP2F(x) __builtin_amdgcn_exp2f(x)
#else
#define EXP2F(x) exp2f(x)
#endif
#if __has_builtin(__builtin_amdgcn_rcpf)
#define RCPF(x) __builtin_amdgcn_rcpf(x)
#else
#define RCPF(x) (1.0f / (x))
#endif

#define LOG2E 1.4426950408889634f

__device__ __forceinline__ u16 f2b(float f) {
  uint32_t u = __builtin_bit_cast(uint32_t, f);
  u = u + 0x7FFFu + ((u >> 16) & 1u);
  return (u16)(u >> 16);
}
__device__ __forceinline__ float b2f(u16 s) {
  uint32_t u = ((uint32_t)s) << 16;
  return __builtin_bit_cast(float, u);
}
__device__ __forceinline__ float fast_tanh(float x) {
  return 1.0f - 2.0f * RCPF(EXP2F(2.0f * LOG2E * x) + 1.0f);
}
__device__ __forceinline__ uint32_t cvtpk(float a, float b) {
  uint32_t r;
  asm("v_cvt_pk_bf16_f32 %0, %1, %2" : "=v"(r) : "v"(a), "v"(b));
  return r;
}

// ---------------------------------------------------------------------------
// prep: grid 448 x 256 (identical to v8)
// ---------------------------------------------------------------------------
__global__ void prep_kernel(
    const float* __restrict__ emb,
    const float* __restrict__ wih_f, const float* __restrict__ bih_f,
    const float* __restrict__ wih_b, const float* __restrict__ bih_b,
    const float* __restrict__ bhh_f, const float* __restrict__ bhh_b,
    const float* __restrict__ whh_f_in, const float* __restrict__ whh_b_in,
    const float* __restrict__ wp_in,
    float* __restrict__ xpf_f, float* __restrict__ xpf_b,
    u16* __restrict__ whhf, u16* __restrict__ whhb, u16* __restrict__ wpf) {
  int gid = blockIdx.x * 256 + threadIdx.x;
  if (blockIdx.x < 384) {
    int e = gid;                    // 0..98303
    int d = (e >= 49152) ? 1 : 0;
    int r = e - d * 49152;
    int j = r & 3;
    int e2 = r >> 2;                // 12288
    int cls = e2 % 3;
    int e3 = e2 / 3;                // 4096
    int grp = e3 & 3;
    int e4 = e3 >> 2;               // 1024
    int wv = e4 & 7;
    int c = e4 >> 3;                // 128
    int row = cls * 128 + wv * 16 + grp * 4 + j;
    const float* wih = d ? wih_b : wih_f;
    const float* bih = d ? bih_b : bih_f;
    const float* bhh = d ? bhh_b : bhh_f;
    const float4* e4p = (const float4*)(emb + c * 64);
    const float4* w4p = (const float4*)(wih + row * 64);
    float s = 0.f;
#pragma unroll
    for (int q = 0; q < 16; q++) {
      float4 a = e4p[q], b = w4p[q];
      s += a.x * b.x + a.y * b.y + a.z * b.z + a.w * b.w;
    }
    s += bih[row];
    float scale;
    if (cls < 2) {
      s += bhh[row];
      scale = -LOG2E;
    } else {
      scale = 2.0f * LOG2E;
    }
    (d ? xpf_b : xpf_f)[r] = s * scale;
  } else if (blockIdx.x < 432) {
    int idx = gid - 384 * 256;  // 0..12287
    int d = (idx >= 6144) ? 1 : 0;
    int r = idx - d * 6144;
    int lane = r & 63, kt = (r >> 6) & 3, nt = r >> 8;
    float scale = (nt < 16) ? -LOG2E : 2.0f * LOG2E;  // cls = nt>>3
    int n = nt * 16 + (lane & 15);
    int k0 = kt * 32 + (lane >> 4) * 8;
    const float* w = d ? whh_b_in : whh_f_in;
    u16* o = (d ? whhb : whhf) + r * 8;
    for (int j = 0; j < 8; j++) o[j] = f2b(w[n * 128 + k0 + j] * scale);
  } else {
    int idx = gid - 432 * 256;  // 0..4095
    if (idx < 4096) {
      int lane = idx & 63, kt = (idx >> 6) & 7, nt = idx >> 9;
      int n = nt * 16 + (lane & 15);
      int k0 = kt * 32 + (lane >> 4) * 8;
      u16* o = wpf + idx * 8;
      for (int j = 0; j < 8; j++) o[j] = f2b(wp_in[n * 256 + k0 + j]);
    }
  }
}

// ---------------------------------------------------------------------------
// counting sort by length (bins 1..20); c0 = pad-position attention score.
// ---------------------------------------------------------------------------
__global__ void sort_zero(int* __restrict__ bins) {
  if (threadIdx.x < 32) bins[threadIdx.x] = 0;
}
__global__ void sort_hist(const int* __restrict__ lens, int* __restrict__ bins) {
  __shared__ int hcnt[32];
  int tid = threadIdx.x;
  if (tid < 32) hcnt[tid] = 0;
  __syncthreads();
  int gid = blockIdx.x * 256 + tid;
  int l = lens[gid] & 31;
  atomicAdd(&hcnt[l], 1);
  __syncthreads();
  if (tid < 32 && hcnt[tid]) atomicAdd(&bins[tid], hcnt[tid]);
}
__global__ void sort_scan(const int* __restrict__ bins, int* __restrict__ offsw,
                          const float* __restrict__ bp,
                          const float* __restrict__ ctx,
                          float* __restrict__ c0out) {
  if (threadIdx.x == 0 && blockIdx.x == 0) {
    int off = 0;
    for (int l = 0; l < 32; l++) {
      offsw[l] = off;
      off += bins[l];
    }
    float c0 = 0.f;
    for (int c = 0; c < 128; c++) c0 += fast_tanh(bp[c]) * ctx[c];
    *c0out = c0;
  }
}
__global__ void sort_scat(const int* __restrict__ lens, int* __restrict__ offsw,
                          int* __restrict__ perm) {
  __shared__ int lcnt[32];
  __shared__ int lbase[32];
  int tid = threadIdx.x;
  if (tid < 32) lcnt[tid] = 0;
  __syncthreads();
  int gid = blockIdx.x * 256 + tid;
  int l = lens[gid] & 31;
  int lr = atomicAdd(&lcnt[l], 1);
  __syncthreads();
  if (tid < 32) lbase[tid] = lcnt[tid] ? atomicAdd(&offsw[tid], lcnt[tid]) : 0;
  __syncthreads();
  perm[lbase[l] + lr] = gid;
}

// ---------------------------------------------------------------------------
// gru_nobar: grid 2*nbd x 512. bid parity = direction; 128 sorted words per
// block = 8 INDEPENDENT waves x 16 words. Whh' frag table in LDS (96 KiB,
// shared); per-wave private h-pack (4 KiB) written at v8-verified hw_off(nt)
// slots and re-read as B-frags next step. NO barrier in the step loop.
// ---------------------------------------------------------------------------
__global__ __launch_bounds__(512, 2) void gru_nobar(
    const int* __restrict__ chars, const int* __restrict__ lens,
    const int* __restrict__ perm,
    const float* __restrict__ xpf_f, const float* __restrict__ xpf_b,
    const u16* __restrict__ whhf, const u16* __restrict__ whhb,
    const float* __restrict__ bhh_f, const float* __restrict__ bhh_b,
    u16* __restrict__ hf, u16* __restrict__ hb, int word_off, int nbd) {
  const int bid = blockIdx.x;
  const int dir = bid & 1;
  const int wg = nbd - 1 - (bid >> 1);  // longest-first
  const int tid = threadIdx.x;

  __shared__ u16 whh_s[49152];              // 96 KiB frag table (one dir)
  __shared__ u16 pack_s[8][2048];           // 8 x 4 KiB per-wave h-pack
  __shared__ unsigned char chars_s[2560];   // [s:20][w:128] pre-remapped
  __shared__ unsigned char lens_s[128];

  const u16* whh = dir ? whhb : whhf;
  const float* xp = dir ? xpf_b : xpf_f;
  const float* bhh = dir ? bhh_b : bhh_f;

  if (tid < 128) lens_s[tid] = (unsigned char)lens[perm[word_off + wg * 128 + tid]];
  {
    const uint4* src = (const uint4*)whh;
    uint4* dst = (uint4*)whh_s;
#pragma unroll
    for (int i = 0; i < 12; i++) dst[tid + i * 512] = src[tid + i * 512];
  }
  for (int i = tid; i < 8192; i += 512) ((uint32_t*)pack_s)[i] = 0u;
  __syncthreads();  // lens_s ready (chars staging reads it)
  for (int i = tid; i < 2560; i += 512) {
    int w = i & 127, s = i >> 7;
    int L = lens_s[w];
    int t = dir ? ((s < L) ? (L - 1 - s) : s) : s;
    chars_s[s * 128 + w] = (unsigned char)chars[perm[word_off + wg * 128 + w] * 20 + t];
  }
  __syncthreads();  // chars_s + pack zero + whh_s ready — LAST barrier

  const int wv = tid >> 6, ln = tid & 63, word = ln & 15, grp = ln >> 4;
  const int wl = wv * 16 + word;            // block-local word
  const int Lw = lens_s[wl];
  const int Lmax = lens_s[wv * 16 + 15];    // per-wave trip count (sorted)

  u16* hout = (dir ? hb : hf) + (size_t)(wg * 128 + wl) * 2560 + grp * 4;

  char* pb = (char*)pack_s[wv];
  const char* ws_ = (const char*)whh_s;

  // bhh_n (scaled 2log2e), all 8 nt: 32 regs
  f32x4 bhn[8];
#pragma unroll
  for (int nt = 0; nt < 8; nt++) {
    float4 t4 = *(const float4*)(bhh + 256 + nt * 16 + grp * 4);
    bhn[nt] = (f32x4){t4.x * 2.0f * LOG2E, t4.y * 2.0f * LOG2E,
                      t4.z * 2.0f * LOG2E, t4.w * 2.0f * LOG2E};
  }

  float h[8][4];
#pragma unroll
  for (int nt = 0; nt < 8; nt++)
#pragma unroll
    for (int r = 0; r < 4; r++) h[nt][r] = 0.f;

  const float* xpg = xp + grp * 12;

  for (int s = 0; s < Lmax; s++) {
    // B-frags for this step (written by THIS wave last step; in-order DS,
    // data-dependent -> no barrier needed)
    bf16x8 Hf[4];
#pragma unroll
    for (int kt = 0; kt < 4; kt++)
      Hf[kt] = *(const bf16x8*)(pb + ((kt * 64 + ln) << 4));

    int c = chars_s[s * 128 + wl];
    const float* xr = xpg + (c << 8) + (c << 7);  // + c*384
    int t = dir ? (Lw - 1 - s) : s;
    bool valid = (s < Lw);

#pragma unroll
    for (int nt = 0; nt < 8; nt++) {
      f32x4 x0 = *(const f32x4*)(xr + nt * 48);
      f32x4 x1 = *(const f32x4*)(xr + nt * 48 + 4);
      f32x4 x2 = *(const f32x4*)(xr + nt * 48 + 8);
      f32x4 a0 = (f32x4){0.f, 0.f, 0.f, 0.f};
      f32x4 a1 = (f32x4){0.f, 0.f, 0.f, 0.f};
      f32x4 a2 = bhn[nt];
#pragma unroll
      for (int kt = 0; kt < 4; kt++) {
        bf16x8 A0 = *(const bf16x8*)(ws_ + ((((0 * 8 + nt) * 4 + kt) * 64 + ln) << 4));
        a0 = __builtin_amdgcn_mfma_f32_16x16x32_bf16(A0, Hf[kt], a0, 0, 0, 0);
        bf16x8 A1 = *(const bf16x8*)(ws_ + ((((1 * 8 + nt) * 4 + kt) * 64 + ln) << 4));
        a1 = __builtin_amdgcn_mfma_f32_16x16x32_bf16(A1, Hf[kt], a1, 0, 0, 0);
        bf16x8 A2 = *(const bf16x8*)(ws_ + ((((2 * 8 + nt) * 4 + kt) * 64 + ln) << 4));
        a2 = __builtin_amdgcn_mfma_f32_16x16x32_bf16(A2, Hf[kt], a2, 0, 0, 0);
      }
#pragma unroll
      for (int r = 0; r < 4; r++) {
        float rr = RCPF(1.0f + EXP2F(x0[r] + a0[r]));
        float zz = RCPF(1.0f + EXP2F(x1[r] + a1[r]));
        float na = fmaf(rr, a2[r], x2[r]);
        float nn = fmaf(-2.0f, RCPF(EXP2F(na) + 1.0f), 1.0f);
        h[nt][r] = fmaf(zz, h[nt][r] - nn, nn);
      }
      uint2 pk = make_uint2(cvtpk(h[nt][0], h[nt][1]), cvtpk(h[nt][2], h[nt][3]));
      // pack write: v8-verified mapping with nt as hid-tile owner
      int pw = ((((nt >> 1) << 6) + (word | (((nt & 1) * 2 + (grp >> 1)) << 4))) << 4) +
               ((grp & 1) << 3);
      *(uint2*)(pb + pw) = pk;
      if (valid) *(uint2*)(hout + t * 128 + nt * 16) = pk;
    }
  }
}

// ---------------------------------------------------------------------------
// attn: grid nbA x 256. 16 sorted words/block, 16 threads/word (facc[16]).
// Exact v8-proven version.
// ---------------------------------------------------------------------------
__global__ __launch_bounds__(256, 2) void attn_kernel(
    const u16* __restrict__ hf, const u16* __restrict__ hb,
    const u16* __restrict__ wpf,
    const float* __restrict__ bp, const float* __restrict__ ctx,
    const int* __restrict__ perm, const int* __restrict__ lens,
    const float* __restrict__ c0p,
    float* __restrict__ out, int word_off) {
  const int blk = gridDim.x - 1 - blockIdx.x;  // longest-first
  const int lw0 = blk * 16;

  __shared__ u16 ot_s[4096];       // 8 KiB: Out_t frag layout (16x256)
  __shared__ float part_s[4][16];
  __shared__ int perm_s[16];
  __shared__ unsigned char lens_s[16];

  const int tid = threadIdx.x;
  const int wv = tid >> 6, ln = tid & 63, col = ln & 15, grp = ln >> 4;
  const int sw = tid >> 4;   // this thread's word (16 threads per word)
  const int seg = tid & 15;  // 16-dim segment of the 256-dim output

  if (tid < 16) {
    int p = perm[word_off + lw0 + tid];
    perm_s[tid] = p;
    lens_s[tid] = (unsigned char)lens[p];
  }
  __syncthreads();
  const int Lmax = lens_s[15];  // sorted ascending within block
  const int Lw = lens_s[sw];

  float bpv[2], ctxv[2];
#pragma unroll
  for (int n = 0; n < 2; n++) {
    int nt = wv + n * 4;
    bpv[n] = bp[nt * 16 + col];
    ctxv[n] = ctx[nt * 16 + col];
  }

  float facc[16];
#pragma unroll
  for (int i = 0; i < 16; i++) facc[i] = 0.f;
  float mrun = -3.0e38f, drun = 0.f;

  // seg 0..7 -> hf dims [seg*16,+16); seg 8..15 -> hb dims [(seg-8)*16,+16)
  const u16* srcbase =
      ((seg < 8) ? hf : hb) + (size_t)(lw0 + sw) * 2560 + (seg & 7) * 16;

  uint4 vn[2];
#pragma unroll
  for (int q = 0; q < 2; q++) vn[q] = *(const uint4*)(srcbase + q * 8);

  for (int t = 0; t < Lmax; t++) {
    uint4 v[2];
    v[0] = vn[0];
    v[1] = vn[1];

    // stage Out_t into frag layout: k = seg*16 + q*8
#pragma unroll
    for (int q = 0; q < 2; q++) {
      int idx = seg * 2 + q;           // k>>3, 0..31
      int kt = idx >> 2;               // k>>5
      int lane_a = sw | ((idx & 3) << 4);
      *(uint4*)(ot_s + ((kt * 64 + lane_a) << 3)) = v[q];
    }
    // prefetch next t (hidden under MFMA/score)
    if (t + 1 < Lmax) {
      const u16* src = srcbase + (t + 1) * 128;
#pragma unroll
      for (int q = 0; q < 2; q++) vn[q] = *(const uint4*)(src + q * 8);
    }
    __syncthreads();

    // proj = Out_t @ Wp^T + bp (Wp frags from L2)
    f32x4 acc[2];
#pragma unroll
    for (int n = 0; n < 2; n++) acc[n] = (f32x4){bpv[n], bpv[n], bpv[n], bpv[n]};

#pragma unroll
    for (int kt = 0; kt < 8; kt++) {
      bf16x8 Af = *(const bf16x8*)(ot_s + ((kt * 64 + ln) << 3));
#pragma unroll
      for (int n = 0; n < 2; n++) {
        int nt = wv + n * 4;
        bf16x8 Bf = *(const bf16x8*)(wpf + (((nt * 8 + kt) * 64 + ln) << 3));
        acc[n] = __builtin_amdgcn_mfma_f32_16x16x32_bf16(Af, Bf, acc[n], 0, 0, 0);
      }
    }

    // score partials: tanh(proj)*ctx summed over cols; words at (grp*4+r)
#pragma unroll
    for (int r = 0; r < 4; r++) {
      float p = fast_tanh(acc[0][r]) * ctxv[0] + fast_tanh(acc[1][r]) * ctxv[1];
      p += __shfl_xor(p, 1, 64);
      p += __shfl_xor(p, 2, 64);
      p += __shfl_xor(p, 4, 64);
      p += __shfl_xor(p, 8, 64);
      if (col == 0) part_s[wv][grp * 4 + r] = p;
    }
    __syncthreads();

    float sc = part_s[0][sw] + part_s[1][sw] + part_s[2][sw] + part_s[3][sw];

    if (t < Lw) {
      float mnew = fmaxf(mrun, sc);
      float scale = EXP2F(LOG2E * (mrun - mnew));
      float e = EXP2F(LOG2E * (sc - mnew));
      drun = drun * scale + e;
      mrun = mnew;
#pragma unroll
      for (int q = 0; q < 2; q++) {
        const u16* pv = (const u16*)&v[q];
#pragma unroll
        for (int j = 0; j < 8; j++)
          facc[q * 8 + j] = facc[q * 8 + j] * scale + e * b2f(pv[j]);
      }
    }
  }

  // reference semantics: softmax over all 20 positions; pad rows are zero
  // with constant score c0 -> denominator-only mass.
  drun += (float)(20 - Lw) * EXP2F(LOG2E * (*c0p - mrun));

  float inv = RCPF(drun);
  float* dst = out + (size_t)perm_s[sw] * 256 + seg * 16;
#pragma unroll
  for (int i = 0; i < 4; i++) {
    float4 o = make_float4(facc[i * 4] * inv, facc[i * 4 + 1] * inv,
                           facc[i * 4 + 2] * inv, facc[i * 4 + 3] * inv);
    *(float4*)(dst + i * 4) = o;
  }
}

// ---------------------------------------------------------------------------
extern "C" void kernel_launch(void* const* d_in, const int* in_sizes, int n_in,
                              void* d_out, int out_size, void* d_ws, size_t ws_size,
                              hipStream_t stream) {
  const int* chars = (const int*)d_in[0];
  const int* lens = (const int*)d_in[1];
  const float* emb = (const float*)d_in[2];
  const float* wih_f = (const float*)d_in[3];
  const float* whh_f = (const float*)d_in[4];
  const float* bih_f = (const float*)d_in[5];
  const float* bhh_f = (const float*)d_in[6];
  const float* wih_b = (const float*)d_in[7];
  const float* whh_b = (const float*)d_in[8];
  const float* bih_b = (const float*)d_in[9];
  const float* bhh_b = (const float*)d_in[10];
  const float* wp = (const float*)d_in[11];
  const float* bp = (const float*)d_in[12];
  const float* ctx = (const float*)d_in[13];
  float* outp = (float*)d_out;

  uint8_t* ws = (uint8_t*)d_ws;
  float* xpf_f = (float*)(ws + 0);            // 192 KiB
  float* xpf_b = (float*)(ws + 196608);       // 192 KiB
  u16* whhf = (u16*)(ws + 393216);            // 96 KiB
  u16* whhb = (u16*)(ws + 491520);            // 96 KiB
  u16* wpf = (u16*)(ws + 589824);             // 64 KiB
  int* bins = (int*)(ws + 655360);            // 128 B
  int* offsw = (int*)(ws + 655488);           // 128 B
  float* c0p = (float*)(ws + 655616);         // 64 B
  int* permp = (int*)(ws + 655680);           // 128 KiB
  const size_t H_OFF = 1048576;

  prep_kernel<<<448, 256, 0, stream>>>(emb, wih_f, bih_f, wih_b, bih_b, bhh_f,
                                       bhh_b, whh_f, whh_b, wp, xpf_f, xpf_b,
                                       whhf, whhb, wpf);
  sort_zero<<<1, 64, 0, stream>>>(bins);
  sort_hist<<<128, 256, 0, stream>>>(lens, bins);
  sort_scan<<<1, 64, 0, stream>>>(bins, offsw, bp, ctx, c0p);
  sort_scat<<<128, 256, 0, stream>>>(lens, offsw, permp);

  const size_t per_word = 20 * 128 * 2 * 2;  // hf+hb bytes per word
  size_t avail = (ws_size > H_OFF) ? (ws_size - H_OFF) : 0;
  int maxw = (int)(avail / per_word) & ~127;
  if (maxw > 32768) maxw = 32768;
  if (maxw < 128) maxw = 128;

  for (int done = 0; done < 32768;) {
    int nw = (32768 - done < maxw) ? (32768 - done) : maxw;
    u16* hfp = (u16*)(ws + H_OFF);
    u16* hbp = hfp + (size_t)nw * 2560;
    int nbd = nw / 128;
    gru_nobar<<<2 * nbd, 512, 0, stream>>>(chars, lens, permp, xpf_f, xpf_b,
                                           whhf, whhb, bhh_f, bhh_b, hfp, hbp,
                                           done, nbd);
    attn_kernel<<<nw / 16, 256, 0, stream>>>(hfp, hbp, wpf, bp, ctx, permp,
                                             lens, c0p, outp, done);
    done += nw;
  }
}

// Round 14
// 262.843 us; speedup vs baseline: 1.2814x; 1.2814x over previous
//
#include <hip/hip_runtime.h>
#include <hip/hip_bf16.h>
#include <stdint.h>

// ---------------------------------------------------------------------------
// CharToWord v14 == v6 (empirical best, 262.8 us): bidirectional char-GRU +
// attention pooling.
// Session summary: 8 gru structures measured (occupancy x2, VALU -40%,
// dual-chain ILP, lgkm-only barriers, 2x tile, conflict-free store, attn
// fusion, no-barrier LDS-Whh) — all within +/-10% or worse; only work
// REMOVAL ever moved total time (xp table lookup, length sort, spill
// elimination). v6 configuration:
//  - gru: 512 thr / 8 waves; wave owns (hid-group hg, j2-half) -> 3 n-tiles
//    (Bf 48 VGPRs), 4 gate-elems/thread; bf16 xp table (uint2/thread; lowest
//    L2 traffic of all variants); h_s frag-linear double-buffer, 1 barrier
//    per step; LPT block order; counting sort by length.
//  - attn: 16 sorted words/block, 16 thr/word (facc[16], ~85 regs, no
//    spill), register double-buffer prefetch, online softmax + pad mass
//    (20-L)*e^{c0} (reference softmax runs over all 20 positions).
// ---------------------------------------------------------------------------

typedef unsigned short u16;
typedef float f32x4 __attribute__((ext_vector_type(4)));
typedef __bf16 bf16x8 __attribute__((ext_vector_type(8)));

#if __has_builtin(__builtin_amdgcn_exp2f)
#define EXP2F(x) __builtin_amdgcn_exp2f(x)
#else
#define EXP2F(x) exp2f(x)
#endif
#if __has_builtin(__builtin_amdgcn_rcpf)
#define RCPF(x) __builtin_amdgcn_rcpf(x)
#else
#define RCPF(x) (1.0f / (x))
#endif

#define LOG2E 1.4426950408889634f

__device__ __forceinline__ u16 f2b(float f) {
  uint32_t u = __builtin_bit_cast(uint32_t, f);
  u = u + 0x7FFFu + ((u >> 16) & 1u);
  return (u16)(u >> 16);
}
__device__ __forceinline__ float b2f(u16 s) {
  uint32_t u = ((uint32_t)s) << 16;
  return __builtin_bit_cast(float, u);
}
__device__ __forceinline__ float fast_sig(float x) {
  return RCPF(1.0f + EXP2F(-LOG2E * x));
}
__device__ __forceinline__ float fast_tanh(float x) {
  return 1.0f - 2.0f * RCPF(EXP2F(2.0f * LOG2E * x) + 1.0f);
}

// ---------------------------------------------------------------------------
// prep: grid 1088 x 256
//  blocks [0,1024)    : xp tables (bf16), idx ((c*2+j2)*128 + w16)*4 + slot,
//                       slot = gate class (r,z,n, pad); w16 = hg*16+col
//  blocks [1024,1072) : Whh frag bf16, chunks ((nt*4+kt)*64+lane)*8
//  blocks [1072,1088) : Wp frag bf16,  chunks ((nt*8+kt)*64+lane)*8
// ---------------------------------------------------------------------------
__global__ void prep_kernel(
    const float* __restrict__ emb,
    const float* __restrict__ wih_f, const float* __restrict__ bih_f,
    const float* __restrict__ wih_b, const float* __restrict__ bih_b,
    const float* __restrict__ whh_f_in, const float* __restrict__ whh_b_in,
    const float* __restrict__ wp_in,
    u16* __restrict__ xpj_f, u16* __restrict__ xpj_b,
    u16* __restrict__ whhf, u16* __restrict__ whhb, u16* __restrict__ wpf) {
  int gid = blockIdx.x * 256 + threadIdx.x;
  if (blockIdx.x < 1024) {
    int d = gid >> 17;          // 131072 entries per direction
    int r = gid & 131071;
    int c = r >> 10;            // 1024 per char
    int r2 = r & 1023;
    int j2 = r2 >> 9;
    int r3 = r2 & 511;
    int w16 = r3 >> 2;          // hg*16 + col
    int slot = r3 & 3;
    float v = 0.f;
    if (slot < 3) {
      int gate = slot * 128 + (w16 >> 4) * 32 + j2 * 16 + (w16 & 15);
      const float* wih = d ? wih_b : wih_f;
      const float* bih = d ? bih_b : bih_f;
      const float4* e4 = (const float4*)(emb + c * 64);
      const float4* w4 = (const float4*)(wih + gate * 64);
      float s = 0.f;
#pragma unroll
      for (int e = 0; e < 16; e++) {
        float4 a = e4[e], b = w4[e];
        s += a.x * b.x + a.y * b.y + a.z * b.z + a.w * b.w;
      }
      v = s + bih[gate];
    }
    (d ? xpj_b : xpj_f)[r] = f2b(v);
  } else if (blockIdx.x < 1072) {
    int idx = gid - 1024 * 256;  // 0..12287
    int d = (idx >= 6144) ? 1 : 0;
    int r = idx - d * 6144;
    int lane = r & 63, kt = (r >> 6) & 3, nt = r >> 8;
    int n = nt * 16 + (lane & 15);
    int k0 = kt * 32 + (lane >> 4) * 8;
    const float* w = d ? whh_b_in : whh_f_in;
    u16* o = (d ? whhb : whhf) + r * 8;
    for (int j = 0; j < 8; j++) o[j] = f2b(w[n * 128 + k0 + j]);
  } else {
    int idx = gid - 1072 * 256;  // 0..4095
    if (idx < 4096) {
      int lane = idx & 63, kt = (idx >> 6) & 7, nt = idx >> 9;
      int n = nt * 16 + (lane & 15);
      int k0 = kt * 32 + (lane >> 4) * 8;
      u16* o = wpf + idx * 8;
      for (int j = 0; j < 8; j++) o[j] = f2b(wp_in[n * 256 + k0 + j]);
    }
  }
}

// ---------------------------------------------------------------------------
// counting sort by length (bins 1..20); c0 = pad-position attention score.
// ---------------------------------------------------------------------------
__global__ void sort_zero(int* __restrict__ bins) {
  if (threadIdx.x < 32) bins[threadIdx.x] = 0;
}
__global__ void sort_hist(const int* __restrict__ lens, int* __restrict__ bins) {
  __shared__ int hcnt[32];
  int tid = threadIdx.x;
  if (tid < 32) hcnt[tid] = 0;
  __syncthreads();
  int gid = blockIdx.x * 256 + tid;
  int l = lens[gid] & 31;
  atomicAdd(&hcnt[l], 1);
  __syncthreads();
  if (tid < 32 && hcnt[tid]) atomicAdd(&bins[tid], hcnt[tid]);
}
__global__ void sort_scan(const int* __restrict__ bins, int* __restrict__ offsw,
                          const float* __restrict__ bp,
                          const float* __restrict__ ctx,
                          float* __restrict__ c0out) {
  if (threadIdx.x == 0 && blockIdx.x == 0) {
    int off = 0;
    for (int l = 0; l < 32; l++) {
      offsw[l] = off;
      off += bins[l];
    }
    float c0 = 0.f;
    for (int c = 0; c < 128; c++) c0 += fast_tanh(bp[c]) * ctx[c];
    *c0out = c0;
  }
}
__global__ void sort_scat(const int* __restrict__ lens, int* __restrict__ offsw,
                          int* __restrict__ perm) {
  __shared__ int lcnt[32];
  __shared__ int lbase[32];
  int tid = threadIdx.x;
  if (tid < 32) lcnt[tid] = 0;
  __syncthreads();
  int gid = blockIdx.x * 256 + tid;
  int l = lens[gid] & 31;
  int lr = atomicAdd(&lcnt[l], 1);
  __syncthreads();
  if (tid < 32) lbase[tid] = lcnt[tid] ? atomicAdd(&offsw[tid], lcnt[tid]) : 0;
  __syncthreads();
  perm[lbase[l] + lr] = gid;
}

// ---------------------------------------------------------------------------
// gru: grid 2*nbd x 512. bid parity = direction; 16 sorted words/block.
// 8 waves: wave wv -> (hg = wv>>1, j2 = wv&1), 3 n-tiles nt = cls*8+hg*2+j2.
// Bf 48 regs/thread; 4 gate-elems/thread; h_s double-buffer, 1 barrier/step.
// LPT: wg reversed so longest blocks launch first.
// ---------------------------------------------------------------------------
__global__ __launch_bounds__(512, 4) void gru_kernel(
    const int* __restrict__ chars, const int* __restrict__ lens,
    const int* __restrict__ perm,
    const u16* __restrict__ xpj_f, const u16* __restrict__ xpj_b,
    const u16* __restrict__ whhf, const u16* __restrict__ whhb,
    const float* __restrict__ bhh_f, const float* __restrict__ bhh_b,
    u16* __restrict__ hf, u16* __restrict__ hb, int word_off, int nbd) {
  const int bid = blockIdx.x;
  const int dir = bid & 1;
  const int wg = nbd - 1 - (bid >> 1);  // longest-first (perm ascending)
  const int tid = threadIdx.x;

  __shared__ int perm_s[16];
  __shared__ unsigned char lens_s[16];
  __shared__ unsigned char chars_s[320];  // [s][w] pre-remapped
  __shared__ u16 h_s[2][2048];            // double-buffered A-frag layout

  if (tid < 16) {
    int p = perm[word_off + wg * 16 + tid];
    perm_s[tid] = p;
    lens_s[tid] = (unsigned char)lens[p];
  }
  for (int i = tid; i < 1024; i += 512) ((uint32_t*)h_s[0])[i] = 0u;
  __syncthreads();

  for (int i = tid; i < 320; i += 512) {
    int w = i & 15, s = i >> 4;
    int L = lens_s[w];
    int t = dir ? ((s < L) ? (L - 1 - s) : s) : s;
    chars_s[s * 16 + w] = (unsigned char)chars[perm_s[w] * 20 + t];
  }

  const u16* xp = dir ? xpj_b : xpj_f;
  const u16* whh = dir ? whhb : whhf;
  const float* bhh = dir ? bhh_b : bhh_f;
  u16* hout = (dir ? hb : hf) + (size_t)wg * 16 * 2560;

  const int wv = tid >> 6, ln = tid & 63, col = ln & 15, grp = ln >> 4;
  const int j2 = wv & 1, hg = wv >> 1;

  // Whh B-fragments -> 48 VGPRs, once per block
  bf16x8 Bf[3][4];
#pragma unroll
  for (int cls = 0; cls < 3; cls++) {
    int nt = cls * 8 + hg * 2 + j2;
#pragma unroll
    for (int kt = 0; kt < 4; kt++)
      Bf[cls][kt] = *(const bf16x8*)(whh + (((nt * 4 + kt) * 64 + ln) << 3));
  }

  float bh[3];
#pragma unroll
  for (int cls = 0; cls < 3; cls++)
    bh[cls] = bhh[cls * 128 + hg * 32 + j2 * 16 + col];

  __syncthreads();  // chars_s + h_s zero ready

  const int Lmax = lens_s[15];  // sorted ascending within block

  // store-phase constants: thread -> (word, 4-dim slice) of 16x128 h tile
  const int swd = tid >> 5;
  const int k4 = (tid & 31) << 2;
  const int skt = k4 >> 5;
  const int slan = swd | (((k4 >> 3) & 3) << 4);
  const int sslot = k4 & 7;
  const int sL = lens_s[swd];

  float h[4] = {0.f, 0.f, 0.f, 0.f};

  // prefetch xq for s=0 (uint2: gate slots r,z,n)
  uint2 xq[4];
#pragma unroll
  for (int r = 0; r < 4; r++) {
    int c = chars_s[grp * 4 + r];
    xq[r] = *(const uint2*)(xp + ((((c << 1) + j2) << 7) + (hg << 4) + col) * 4);
  }

  for (int s = 0; s < Lmax; s++) {
    const u16* hcur = h_s[s & 1];
    u16* hnxt = h_s[(s + 1) & 1];

    uint2 xc[4];
#pragma unroll
    for (int r = 0; r < 4; r++) xc[r] = xq[r];
    if (s + 1 < Lmax) {
#pragma unroll
      for (int r = 0; r < 4; r++) {
        int c = chars_s[(s + 1) * 16 + grp * 4 + r];
        xq[r] =
            *(const uint2*)(xp + ((((c << 1) + j2) << 7) + (hg << 4) + col) * 4);
      }
    }

    f32x4 acc[3];
#pragma unroll
    for (int cls = 0; cls < 3; cls++)
      acc[cls] = (f32x4){bh[cls], bh[cls], bh[cls], bh[cls]};
#pragma unroll
    for (int kt = 0; kt < 4; kt++) {
      bf16x8 Af = *(const bf16x8*)(hcur + ((kt * 64 + ln) << 3));
#pragma unroll
      for (int cls = 0; cls < 3; cls++)
        acc[cls] =
            __builtin_amdgcn_mfma_f32_16x16x32_bf16(Af, Bf[cls][kt], acc[cls], 0, 0, 0);
    }

    // gates (4 elems/thread) + write to OTHER buffer
#pragma unroll
    for (int r = 0; r < 4; r++) {
      const u16* e = (const u16*)&xc[r];
      float rr = fast_sig(b2f(e[0]) + acc[0][r]);
      float zz = fast_sig(b2f(e[1]) + acc[1][r]);
      float nn = fast_tanh(b2f(e[2]) + rr * acc[2][r]);
      float hn = (1.f - zz) * nn + zz * h[r];
      h[r] = hn;
      int lane_a = (grp * 4 + r) | ((j2 * 2 + (col >> 3)) << 4);
      hnxt[((hg * 64 + lane_a) << 3) + (col & 7)] = f2b(hn);
    }
    __syncthreads();  // hnxt complete; hcur reads done

    // store h row (only t < L), 8B/thread, coalesced
    if (s < sL) {
      int tdst = dir ? (sL - 1 - s) : s;
      uint2 v = *(const uint2*)(hnxt + ((skt * 64 + slan) << 3) + sslot);
      *(uint2*)(hout + ((size_t)swd * 20 + tdst) * 128 + k4) = v;
    }
  }
}

// ---------------------------------------------------------------------------
// attn: grid nbA x 256. 16 sorted words/block, 16 threads/word (facc[16]).
// Online softmax over valid t + pad mass (20-L)*e^{c0-mrun}. LPT order.
// ---------------------------------------------------------------------------
__global__ __launch_bounds__(256, 2) void attn_kernel(
    const u16* __restrict__ hf, const u16* __restrict__ hb,
    const u16* __restrict__ wpf,
    const float* __restrict__ bp, const float* __restrict__ ctx,
    const int* __restrict__ perm, const int* __restrict__ lens,
    const float* __restrict__ c0p,
    float* __restrict__ out, int word_off) {
  const int blk = gridDim.x - 1 - blockIdx.x;  // longest-first
  const int lw0 = blk * 16;

  __shared__ u16 ot_s[4096];       // 8 KiB: Out_t frag layout (16x256)
  __shared__ float part_s[4][16];
  __shared__ int perm_s[16];
  __shared__ unsigned char lens_s[16];

  const int tid = threadIdx.x;
  const int wv = tid >> 6, ln = tid & 63, col = ln & 15, grp = ln >> 4;
  const int sw = tid >> 4;   // this thread's word (16 threads per word)
  const int seg = tid & 15;  // 16-dim segment of the 256-dim output

  if (tid < 16) {
    int p = perm[word_off + lw0 + tid];
    perm_s[tid] = p;
    lens_s[tid] = (unsigned char)lens[p];
  }
  __syncthreads();
  const int Lmax = lens_s[15];  // sorted ascending within block
  const int Lw = lens_s[sw];

  float bpv[2], ctxv[2];
#pragma unroll
  for (int n = 0; n < 2; n++) {
    int nt = wv + n * 4;
    bpv[n] = bp[nt * 16 + col];
    ctxv[n] = ctx[nt * 16 + col];
  }

  float facc[16];
#pragma unroll
  for (int i = 0; i < 16; i++) facc[i] = 0.f;
  float mrun = -3.0e38f, drun = 0.f;

  // seg 0..7 -> hf dims [seg*16,+16); seg 8..15 -> hb dims [(seg-8)*16,+16)
  const u16* srcbase =
      ((seg < 8) ? hf : hb) + (size_t)(lw0 + sw) * 2560 + (seg & 7) * 16;

  uint4 vn[2];
#pragma unroll
  for (int q = 0; q < 2; q++) vn[q] = *(const uint4*)(srcbase + q * 8);

  for (int t = 0; t < Lmax; t++) {
    uint4 v[2];
    v[0] = vn[0];
    v[1] = vn[1];

    // stage Out_t into frag layout: k = seg*16 + q*8
#pragma unroll
    for (int q = 0; q < 2; q++) {
      int idx = seg * 2 + q;           // k>>3, 0..31
      int kt = idx >> 2;               // k>>5
      int lane_a = sw | ((idx & 3) << 4);
      *(uint4*)(ot_s + ((kt * 64 + lane_a) << 3)) = v[q];
    }
    // prefetch next t (hidden under MFMA/score)
    if (t + 1 < Lmax) {
      const u16* src = srcbase + (t + 1) * 128;
#pragma unroll
      for (int q = 0; q < 2; q++) vn[q] = *(const uint4*)(src + q * 8);
    }
    __syncthreads();

    // proj = Out_t @ Wp^T + bp (Wp frags from L2)
    f32x4 acc[2];
#pragma unroll
    for (int n = 0; n < 2; n++) acc[n] = (f32x4){bpv[n], bpv[n], bpv[n], bpv[n]};

#pragma unroll
    for (int kt = 0; kt < 8; kt++) {
      bf16x8 Af = *(const bf16x8*)(ot_s + ((kt * 64 + ln) << 3));
#pragma unroll
      for (int n = 0; n < 2; n++) {
        int nt = wv + n * 4;
        bf16x8 Bf = *(const bf16x8*)(wpf + (((nt * 8 + kt) * 64 + ln) << 3));
        acc[n] = __builtin_amdgcn_mfma_f32_16x16x32_bf16(Af, Bf, acc[n], 0, 0, 0);
      }
    }

    // score partials: tanh(proj)*ctx summed over cols; words at (grp*4+r)
#pragma unroll
    for (int r = 0; r < 4; r++) {
      float p = fast_tanh(acc[0][r]) * ctxv[0] + fast_tanh(acc[1][r]) * ctxv[1];
      p += __shfl_xor(p, 1, 64);
      p += __shfl_xor(p, 2, 64);
      p += __shfl_xor(p, 4, 64);
      p += __shfl_xor(p, 8, 64);
      if (col == 0) part_s[wv][grp * 4 + r] = p;
    }
    __syncthreads();

    float sc = part_s[0][sw] + part_s[1][sw] + part_s[2][sw] + part_s[3][sw];

    if (t < Lw) {
      float mnew = fmaxf(mrun, sc);
      float scale = EXP2F(LOG2E * (mrun - mnew));
      float e = EXP2F(LOG2E * (sc - mnew));
      drun = drun * scale + e;
      mrun = mnew;
#pragma unroll
      for (int q = 0; q < 2; q++) {
        const u16* pv = (const u16*)&v[q];
#pragma unroll
        for (int j = 0; j < 8; j++)
          facc[q * 8 + j] = facc[q * 8 + j] * scale + e * b2f(pv[j]);
      }
    }
  }

  // reference semantics: softmax over all 20 positions; pad rows are zero
  // with constant score c0 -> denominator-only mass.
  drun += (float)(20 - Lw) * EXP2F(LOG2E * (*c0p - mrun));

  float inv = RCPF(drun);
  float* dst = out + (size_t)perm_s[sw] * 256 + seg * 16;
#pragma unroll
  for (int i = 0; i < 4; i++) {
    float4 o = make_float4(facc[i * 4] * inv, facc[i * 4 + 1] * inv,
                           facc[i * 4 + 2] * inv, facc[i * 4 + 3] * inv);
    *(float4*)(dst + i * 4) = o;
  }
}

// ---------------------------------------------------------------------------
extern "C" void kernel_launch(void* const* d_in, const int* in_sizes, int n_in,
                              void* d_out, int out_size, void* d_ws, size_t ws_size,
                              hipStream_t stream) {
  const int* chars = (const int*)d_in[0];
  const int* lens = (const int*)d_in[1];
  const float* emb = (const float*)d_in[2];
  const float* wih_f = (const float*)d_in[3];
  const float* whh_f = (const float*)d_in[4];
  const float* bih_f = (const float*)d_in[5];
  const float* bhh_f = (const float*)d_in[6];
  const float* wih_b = (const float*)d_in[7];
  const float* whh_b = (const float*)d_in[8];
  const float* bih_b = (const float*)d_in[9];
  const float* bhh_b = (const float*)d_in[10];
  const float* wp = (const float*)d_in[11];
  const float* bp = (const float*)d_in[12];
  const float* ctx = (const float*)d_in[13];
  float* outp = (float*)d_out;

  uint8_t* ws = (uint8_t*)d_ws;
  u16* xpj_f = (u16*)(ws + 0);                // 256 KiB
  u16* xpj_b = (u16*)(ws + 262144);           // 256 KiB
  u16* whhf = (u16*)(ws + 524288);            // 96 KiB
  u16* whhb = (u16*)(ws + 622592);            // 96 KiB
  u16* wpf = (u16*)(ws + 720896);             // 64 KiB
  int* bins = (int*)(ws + 786432);            // 128 B
  int* offsw = (int*)(ws + 786560);           // 128 B
  float* c0p = (float*)(ws + 786688);         // 64 B
  int* permp = (int*)(ws + 786752);           // 128 KiB
  const size_t H_OFF = 1048576;

  prep_kernel<<<1088, 256, 0, stream>>>(emb, wih_f, bih_f, wih_b, bih_b, whh_f,
                                        whh_b, wp, xpj_f, xpj_b, whhf, whhb, wpf);
  sort_zero<<<1, 64, 0, stream>>>(bins);
  sort_hist<<<128, 256, 0, stream>>>(lens, bins);
  sort_scan<<<1, 64, 0, stream>>>(bins, offsw, bp, ctx, c0p);
  sort_scat<<<128, 256, 0, stream>>>(lens, offsw, permp);

  const size_t per_word = 20 * 128 * 2 * 2;  // hf+hb bytes per word
  size_t avail = (ws_size > H_OFF) ? (ws_size - H_OFF) : 0;
  int maxw = (int)(avail / per_word) & ~63;
  if (maxw > 32768) maxw = 32768;
  if (maxw < 64) maxw = 64;

  for (int done = 0; done < 32768;) {
    int nw = (32768 - done < maxw) ? (32768 - done) : maxw;
    u16* hfp = (u16*)(ws + H_OFF);
    u16* hbp = hfp + (size_t)nw * 2560;
    int nbd = nw / 16;
    gru_kernel<<<2 * nbd, 512, 0, stream>>>(chars, lens, permp, xpj_f, xpj_b,
                                            whhf, whhb, bhh_f, bhh_b, hfp, hbp,
                                            done, nbd);
    attn_kernel<<<nw / 16, 256, 0, stream>>>(hfp, hbp, wpf, bp, ctx, permp,
                                             lens, c0p, outp, done);
    done += nw;
  }
}